// Round 13
// baseline (153.405 us; speedup 1.0000x reference)
//
#include <hip/hip_runtime.h>
#include <hip/hip_bf16.h>
#include <math.h>

#define LEN 128
#define NCELLS 8256          // LEN*(LEN+1)/2
#define TOTAL 349504         // sum_{l=1}^{127} (128-l)*l
#define NCONSTR 8
#define BONUS 1000.0f
#define NT 512

// Barrier WITHOUT vmcnt drain: only LDS writes must be ordered; register
// score-prefetch loads stay in flight across the barrier (T4 discipline).
__device__ __forceinline__ void level_barrier() {
    __builtin_amdgcn_sched_barrier(0);
    asm volatile("s_waitcnt lgkmcnt(0)\n\ts_barrier" ::: "memory");
    __builtin_amdgcn_sched_barrier(0);
}

// DPP quad_perm cross-lane max (VALU pipe, no LDS traffic).
__device__ __forceinline__ float dpp_xor1_max(float v) {
    int r = __builtin_amdgcn_update_dpp(0, __float_as_int(v), 0xB1, 0xF, 0xF, true);
    return fmaxf(v, __int_as_float(r));
}
__device__ __forceinline__ float dpp_xor2_max(float v) {
    int r = __builtin_amdgcn_update_dpp(0, __float_as_int(v), 0x4E, 0xF, 0xF, true);
    return fmaxf(v, __int_as_float(r));
}

template<int LG>
__device__ __forceinline__ void redmax2(float& a, float& b) {
    #pragma unroll
    for (int mm = (1 << LG) >> 1; mm >= 4; mm >>= 1) {
        a = fmaxf(a, __shfl_xor(a, mm));
        b = fmaxf(b, __shfl_xor(b, mm));
    }
    if constexpr (LG >= 2) { a = dpp_xor2_max(a); b = dpp_xor2_max(b); }
    if constexpr (LG >= 1) { a = dpp_xor1_max(a); b = dpp_xor1_max(b); }
}

// One CKY level (r4-verified body, RUNTIME level). Phase 1: issue all 2*JM
// independent ds_read_b64 into register arrays; phase 2: consume. Prefetch
// loads level+1 scores into rnxt (in flight across the barrier). JM is the
// REGIME max; per-lane guards (jml) mask the slack so one instance serves a
// whole run of levels from a compact loop body (I$ reuse).
template<int LG, int LG2, int JM, int JM2>
__device__ __forceinline__ void lstep(const int level, int& soff,
        const float* __restrict__ g, float2* __restrict__ chart,
        float (&rcur)[16], float (&rnxt)[16], const int tid)
{
    const int N = level;
    const int L = LEN - level;
    constexpr int T = 1 << LG;
    const int pos = tid >> LG;
    const int sub = tid & (T - 1);
    const int soff_n = soff + L * N;

    // ---- issue next level's score loads (consumed after next barrier) ----
    if constexpr (LG2 >= 0) {
        constexpr int T2 = 1 << LG2;
        const int N2 = level + 1;
        const int L2 = L - 1;
        const int pos2 = tid >> LG2;
        const int sub2 = tid & (T2 - 1);
        if (pos2 < L2) {
            const float* __restrict__ gp = g + soff_n + pos2 * N2 + sub2;
            #pragma unroll
            for (int j = 0; j < JM2; j++) {
                if (sub2 + j * T2 < N2) rnxt[j] = gp[j * T2];
            }
        }
    }

    // ---- compute this level ----
    float bp = -INFINITY, bc = -INFINITY;
    if (pos < L) {
        const int jml = (N - sub + T - 1) >> LG;   // per-lane valid trip count
        float2 lv[JM], rv[JM];
        float  xs[JM];
        #pragma unroll
        for (int j = 0; j < JM; j++) {
            const int n = sub + j * T;
            const int m = level - 1 - n;
            const bool v = (j < jml);
            const int l_idx = ((n * (257 - n)) >> 1) + pos;
            int r_idx = ((m * (257 - m)) >> 1) + pos + n + 1;
            r_idx = v ? r_idx : 0;
            lv[j] = chart[l_idx];
            rv[j] = chart[r_idx];
            xs[j] = v ? rcur[j] : -INFINITY;
        }
        #pragma unroll
        for (int j = 0; j < JM; j++) {
            bp = fmaxf(bp, lv[j].x + rv[j].x + xs[j]);
            bc = fmaxf(bc, lv[j].y + rv[j].y + xs[j]);
        }
    }
    redmax2<LG>(bp, bc);
    if (pos < L && sub == 0) {
        const int q = ((level * (257 - level)) >> 1) + pos;
        float2 c = chart[q];
        c.x += bp;
        c.y += bc;
        chart[q] = c;
    }
    level_barrier();
    soff = soff_n;
}

__global__ __launch_bounds__(NT)
void cky_fused_kernel(const float* __restrict__ scores,
                      const int* __restrict__ cpos,
                      float* __restrict__ ws)
{
    __shared__ float2 chart[NCELLS];   // .x = pred chart, .y = constr chart

    const int b   = blockIdx.x;
    const int tid = threadIdx.x;
    const float* __restrict__ g = scores + (size_t)b * TOTAL;

    float rA[16], rB[16];

    // ---- prefetch level 1 scores (N=1, TPP=4 mapping) ----
    {
        const int pos = tid >> 2;
        const int sub = tid & 3;
        if (pos < 127 && sub == 0) rA[0] = g[pos];
    }
    int cp = 0;
    if (tid < NCONSTR) cp = cpos[b * NCONSTR + tid];

    // ---- init both charts ----
    for (int i = tid; i < NCELLS; i += NT) chart[i] = make_float2(0.f, 0.f);
    level_barrier();
    if (tid < NCONSTR) chart[cp].y = BONUS;   // set (not add); duplicates benign
    level_barrier();

    int soff = 0;

    // ---- TPP=4 regime loops (compact code bodies, runtime level) ----
    #pragma unroll 1
    for (int l = 1; l <= 15; l += 2) {                 // levels 1..16 (JM<=4)
        lstep<2,2,4,5>(l,     soff, g, chart, rA, rB, tid);
        lstep<2,2,4,5>(l + 1, soff, g, chart, rB, rA, tid);
    }
    #pragma unroll 1
    for (int l = 17; l <= 31; l += 2) {                // levels 17..32 (JM<=8)
        lstep<2,2,8,9>(l,     soff, g, chart, rA, rB, tid);
        lstep<2,2,8,9>(l + 1, soff, g, chart, rB, rA, tid);
    }
    #pragma unroll 1
    for (int l = 33; l <= 47; l += 2) {                // levels 33..48 (JM<=12)
        lstep<2,2,12,13>(l,     soff, g, chart, rA, rB, tid);
        lstep<2,2,12,13>(l + 1, soff, g, chart, rB, rA, tid);
    }
    #pragma unroll 1
    for (int l = 49; l <= 61; l += 2) {                // levels 49..62 (JM<=16)
        lstep<2,2,16,16>(l,     soff, g, chart, rA, rB, tid);
        lstep<2,2,16,16>(l + 1, soff, g, chart, rB, rA, tid);
    }
    lstep<2,3,16,8>(63, soff, g, chart, rA, rB, tid);  // prefetch level 64 (T=8)
    // ---- TPP=8: levels 64..95 (JM<=12) ----
    lstep<3,3,12,12>(64, soff, g, chart, rB, rA, tid);
    #pragma unroll 1
    for (int l = 65; l <= 93; l += 2) {
        lstep<3,3,12,12>(l,     soff, g, chart, rA, rB, tid);
        lstep<3,3,12,12>(l + 1, soff, g, chart, rB, rA, tid);
    }
    lstep<3,4,12,7>(95, soff, g, chart, rA, rB, tid);  // prefetch level 96 (T=16)
    // ---- TPP=16: levels 96..111 (JM<=7) ----
    lstep<4,4,7,7>(96, soff, g, chart, rB, rA, tid);
    #pragma unroll 1
    for (int l = 97; l <= 109; l += 2) {
        lstep<4,4,7,7>(l,     soff, g, chart, rA, rB, tid);
        lstep<4,4,7,7>(l + 1, soff, g, chart, rB, rA, tid);
    }
    lstep<4,5,7,4>(111, soff, g, chart, rA, rB, tid);  // prefetch level 112 (T=32)
    // ---- TPP=32: levels 112..119 (JM<=4) ----
    lstep<5,5,4,4>(112, soff, g, chart, rB, rA, tid);
    #pragma unroll 1
    for (int l = 113; l <= 117; l += 2) {
        lstep<5,5,4,4>(l,     soff, g, chart, rA, rB, tid);
        lstep<5,5,4,4>(l + 1, soff, g, chart, rB, rA, tid);
    }
    lstep<5,6,4,2>(119, soff, g, chart, rA, rB, tid);  // prefetch level 120 (T=64)
    // ---- TPP=64: levels 120..127 (JM<=2) ----
    lstep<6,6,2,2>(120, soff, g, chart, rB, rA, tid);
    #pragma unroll 1
    for (int l = 121; l <= 125; l += 2) {
        lstep<6,6,2,2>(l,     soff, g, chart, rA, rB, tid);
        lstep<6,6,2,2>(l + 1, soff, g, chart, rB, rA, tid);
    }
    lstep<6,-1,2,0>(127, soff, g, chart, rA, rB, tid); // root; no prefetch

    // ---- per-batch hinge contribution ----
    if (tid == 0) {
        const float2 f = chart[NCELLS - 1];
        const float pred   = f.x;
        const float constr = f.y - BONUS * NCONSTR;
        const float diff   = pred - constr;
        const float mask   = (fabsf(diff) >= 0.001f) ? 1.f : 0.f;
        const float hinge  = fmaxf(1.0f + diff, 0.f) * mask;
        atomicAdd(ws + 0, hinge);
        atomicAdd(ws + 1, mask);
    }
}

__global__ void final_kernel(const float* __restrict__ ws, float* __restrict__ out) {
    const float h = ws[0];
    const float m = ws[1];
    out[0] = (m > 0.1f) ? (h / fmaxf(m, 1.f)) : h;
}

extern "C" void kernel_launch(void* const* d_in, const int* in_sizes, int n_in,
                              void* d_out, int out_size, void* d_ws, size_t ws_size,
                              hipStream_t stream) {
    const float* scores = (const float*)d_in[0];
    const int*   cpos   = (const int*)d_in[1];
    float* out = (float*)d_out;
    float* ws  = (float*)d_ws;

    hipMemsetAsync(ws, 0, 2 * sizeof(float), stream);
    cky_fused_kernel<<<dim3(256), dim3(NT), 0, stream>>>(scores, cpos, ws);
    final_kernel<<<dim3(1), dim3(1), 0, stream>>>(ws, out);
}